// Round 3
// baseline (215.086 us; speedup 1.0000x reference)
//
#include <hip/hip_runtime.h>
#include <stdint.h>

#define BATCH 32
#define CIN   64
#define HH    112
#define WW    112
#define COUT_ 64

typedef int v4i __attribute__((ext_vector_type(4)));

// d_ws layout
#define WT_OFF   0                      // 36,864 B  weights [co][tap][ci]
#define ZP_OFF   36864                  // 7,296 B   zeroed pad row
#define XT_OFF   65536                  // 26,167,296 B  x int8 [b][h][114 cols][64 ci, swizzled]
#define XT_NEED  (65536 + 26167296)

// Fallback-path weight transpose (also used standalone when ws is small).
__global__ void wtrans_kernel(const int* __restrict__ wq, int8_t* __restrict__ wt) {
    int idx = blockIdx.x * 256 + threadIdx.x;   // 0 .. 36863, exact
    int ci   = idx & 63;
    int khkw = (idx >> 6) % 9;
    int co   = idx / 576;
    wt[idx] = (int8_t)wq[co * 576 + ci * 9 + khkw];
}

// Fused pre-pass: x narrow+NCHW->NHWC transpose (W-pad baked in, ci-chunks
// XOR-swizzled by (col>>1)&3 for conflict-free conv ds_read_b128), pad-col
// zeroing, H-pad zero row, and the weight transpose — one launch.
__global__ void xtrans_kernel(const int* __restrict__ x, const int* __restrict__ wq,
                              int8_t* __restrict__ ws) {
    int8_t* __restrict__ xt = ws + XT_OFF;
    const int bid = blockIdx.x;
    const int tid = threadIdx.x;
    if (bid < 6272) {
        // 32 b x 112 h x 28 colgroups x 16 cigroups = 1,605,632 jobs, exact
        int idx  = bid * 256 + tid;
        int ci4  = idx & 15;            // dword index within the 64B pixel
        int rest = idx >> 4;
        int cg   = rest % 28;           // w = cg*4
        int bh   = rest / 28;           // b*112 + h
        int h    = bh % 112;
        int b    = bh / 112;
        const v4i* gp = (const v4i*)(x + ((b * CIN + ci4 * 4) * HH + h) * WW + cg * 4);
        v4i q0 = gp[0];
        v4i q1 = gp[3136];              // +1 ci plane (112*112/4 int4s)
        v4i q2 = gp[2 * 3136];
        v4i q3 = gp[3 * 3136];
        int8_t* rowp = xt + (size_t)bh * 114 * 64;
        #pragma unroll
        for (int j = 0; j < 4; ++j) {
            uint32_t lo01 = __builtin_amdgcn_perm((uint32_t)q1[j], (uint32_t)q0[j], 0x0C0C0400u);
            uint32_t lo23 = __builtin_amdgcn_perm((uint32_t)q3[j], (uint32_t)q2[j], 0x04000C0Cu);
            int col = cg * 4 + 1 + j;   // +1: W-pad shift
            // chunk (ci4>>2) -> slot (chunk ^ ((col>>1)&3)); dword-in-chunk keeps (ci4&3)
            int sd  = (((ci4 >> 2) ^ ((col >> 1) & 3)) << 2) | (ci4 & 3);
            *(uint32_t*)&rowp[col * 64 + sd * 4] = lo01 | lo23;
        }
    } else if (bid < 6720) {
        // zero pad columns 0 and 113: 32*112*2*16 dwords = 114,688 jobs, exact
        int idx  = (bid - 6272) * 256 + tid;
        int d    = idx & 15;
        int side = (idx >> 4) & 1;
        int bh   = idx >> 5;
        int col  = side ? 113 : 0;
        *(uint32_t*)&xt[((size_t)bh * 114 + col) * 64 + d * 4] = 0u;
    } else if (bid < 6728) {
        // zero the H-pad row (1,824 dwords)
        int idx = (bid - 6720) * 256 + tid;
        if (idx < 1824) *(uint32_t*)&ws[ZP_OFF + idx * 4] = 0u;
    } else {
        // weight transpose: [co][ci][kh][kw] -> [co][tap][ci], 36,864 jobs exact
        int idx  = (bid - 6728) * 256 + tid;
        int ci   = idx & 63;
        int khkw = (idx >> 6) % 9;
        int co   = idx / 576;
        ws[WT_OFF + idx] = (int8_t)wq[co * 576 + ci * 9 + khkw];
    }
}

// Main conv kernel v4. Block = 256 threads (4 waves), one (b, 2-row) tile.
// Stages 4 int8 rows (29,184 B) via global_load_lds; weights preloaded to
// VGPRs; K=64 i8 MFMA; conflict-free swizzled b128 LDS reads; each bfrag
// feeds both output-row accumulators. 4 blocks/CU forced; XCD-chunked
// blockIdx swizzle so h0-adjacent tiles (sharing 2 staged rows) hit L2.
__launch_bounds__(256, 4)
__global__ void conv2_kernel(const int8_t* __restrict__ ws,
                             const float*  __restrict__ wscale,
                             const float*  __restrict__ ascale,
                             const float*  __restrict__ bias,
                             float*        __restrict__ out) {
    __shared__ int8_t xs[4 * 114 * 64];   // 29,184 B

    const int tid = threadIdx.x;
    // XCD-chunked swizzle: 1792 = 8 XCDs x 224 contiguous tiles
    const int bt  = ((blockIdx.x & 7) * 224) + (blockIdx.x >> 3);
    const int b   = bt / 56;
    const int h0  = (bt % 56) * 2;

    const int8_t* __restrict__ xt = ws + XT_OFF;
    const int8_t* __restrict__ zp = ws + ZP_OFF;
    const int8_t* __restrict__ wt = ws + WT_OFF;

    const int lane = tid & 63;
    const int wave = tid >> 6;            // co-tile 0..3
    const int ln15 = lane & 15;
    const int quad = lane >> 4;

    // preload A fragments first (independent of staging; drain together at barrier)
    const v4i* wrow = (const v4i*)(wt + (size_t)(wave * 16 + ln15) * 576);
    v4i a[9];
    #pragma unroll
    for (int t = 0; t < 9; ++t) a[t] = wrow[t * 4 + quad];

    // ---- stage 4 input rows (h0-1 .. h0+2), 1824 x 16B chunks, DMA ----
    #pragma unroll
    for (int i = 0; i < 8; ++i) {
        int idx = tid + i * 256;
        if (idx < 1824) {
            int row = idx / 456;          // 456 chunks per row
            int rem = idx - row * 456;
            int hh  = h0 - 1 + row;
            const int8_t* src = (hh >= 0 && hh < HH)
                ? xt + ((size_t)(b * HH + hh) * 7296 + rem * 16)
                : zp + rem * 16;
            __builtin_amdgcn_global_load_lds(
                (const __attribute__((address_space(1))) int*)src,
                (__attribute__((address_space(3))) int*)(&xs[idx * 16]),
                16, 0, 0);
        }
    }
    __syncthreads();

    v4i acc[2][7];
    #pragma unroll
    for (int r = 0; r < 2; ++r)
        #pragma unroll
        for (int nt = 0; nt < 7; ++nt)
            acc[r][nt] = (v4i){0, 0, 0, 0};

    // Loop over the 4 staged LDS rows; each bfrag serves acc[0] (kh=rho)
    // and acc[1] (kh=rho-1) at the same kw. 84 loads : 126 MFMAs per wave.
    #pragma unroll
    for (int rho = 0; rho < 4; ++rho) {
        #pragma unroll
        for (int kw = 0; kw < 3; ++kw) {
            const int m   = ln15 + kw;                     // pixel col within 16-col tile
            const int swz = (quad ^ ((m >> 1) & 3)) << 4;  // (col>>1)&3 invariant under nt*16
            const int8_t* bp = &xs[(rho * 114 + m) * 64 + swz];
            #pragma unroll
            for (int nt = 0; nt < 7; ++nt) {
                v4i bfrag = *(const v4i*)(bp + nt * 1024);
                if (rho <= 2)
                    acc[0][nt] = __builtin_amdgcn_mfma_i32_16x16x64_i8(
                        a[rho * 3 + kw], bfrag, acc[0][nt], 0, 0, 0);
                if (rho >= 1)
                    acc[1][nt] = __builtin_amdgcn_mfma_i32_16x16x64_i8(
                        a[(rho - 1) * 3 + kw], bfrag, acc[1][nt], 0, 0, 0);
            }
        }
    }

    // ---- fused dequant + bias epilogue (C/D: row = quad*4+reg, col = ln15) ----
    const float s = ascale[0] * wscale[0];
    #pragma unroll
    for (int r = 0; r < 2; ++r) {
        const int h = h0 + r;
        #pragma unroll
        for (int reg = 0; reg < 4; ++reg) {
            int co = wave * 16 + quad * 4 + reg;
            float bv = bias[co];
            float* op = out + ((size_t)(b * COUT_ + co) * HH + h) * WW;
            #pragma unroll
            for (int nt = 0; nt < 7; ++nt)
                op[nt * 16 + ln15] = (float)acc[r][nt][reg] * s + bv;
        }
    }
}

// ---------------- fallback path (small workspace): previous proven kernel ----
__launch_bounds__(256, 2)
__global__ void conv_kernel(const int* __restrict__ x,
                            const int8_t* __restrict__ wt,
                            const float*  __restrict__ wscale,
                            const float*  __restrict__ ascale,
                            const float*  __restrict__ bias,
                            float*        __restrict__ out) {
    __shared__ int8_t xs[4 * 114 * 72];   // 32,832 B

    const int tid = threadIdx.x;
    const int bt  = blockIdx.x;
    const int b   = bt / 56;
    const int h0  = (bt % 56) * 2;

    #pragma unroll
    for (int it = 0; it < 7; ++it) {
        int job = tid + it * 256;
        int ci4 = job & 15;
        int cg  = (job >> 4) % 28;
        int row = job / 448;
        int hh  = h0 - 1 + row;
        v4i q0 = {0,0,0,0}, q1 = {0,0,0,0}, q2 = {0,0,0,0}, q3 = {0,0,0,0};
        if (hh >= 0 && hh < HH) {
            const v4i* gp = (const v4i*)
                (x + ((size_t)(b * CIN + ci4 * 4) * HH + hh) * WW + cg * 4);
            q0 = gp[0];
            q1 = gp[3136];
            q2 = gp[2 * 3136];
            q3 = gp[3 * 3136];
        }
        #pragma unroll
        for (int j = 0; j < 4; ++j) {
            uint32_t lo01 = __builtin_amdgcn_perm((uint32_t)q1[j], (uint32_t)q0[j], 0x0C0C0400u);
            uint32_t lo23 = __builtin_amdgcn_perm((uint32_t)q3[j], (uint32_t)q2[j], 0x04000C0Cu);
            int addr = (row * 114 + cg * 4 + 1 + j) * 72 + ci4 * 4;
            *(uint32_t*)&xs[addr] = lo01 | lo23;
        }
    }
    if (tid < 128) {
        int ci4 = tid & 15;
        int col = ((tid >> 4) & 1) ? 113 : 0;
        int row = tid >> 5;
        *(uint32_t*)&xs[(row * 114 + col) * 72 + ci4 * 4] = 0u;
    }
    __syncthreads();

    const int lane = tid & 63;
    const int wave = tid >> 6;
    const int ln15 = lane & 15;
    const int quad = lane >> 4;
    const int r    = wave >> 1;
    const int coh  = wave & 1;
    const int cobase = coh * 32;

    v4i acc[2][7];
    #pragma unroll
    for (int mt = 0; mt < 2; ++mt)
        #pragma unroll
        for (int nt = 0; nt < 7; ++nt)
            acc[mt][nt] = (v4i){0, 0, 0, 0};

    const long* w64a = (const long*)(wt + (size_t)(cobase + ln15) * 576);
    const long* w64b = (const long*)(wt + (size_t)(cobase + 16 + ln15) * 576);

    #pragma unroll
    for (int kc = 0; kc < 18; ++kc) {
        const int khkw = kc >> 1;
        const int kh   = khkw / 3;
        const int kw   = khkw % 3;
        const int half = kc & 1;
        long a0 = w64a[kc * 4 + quad];
        long a1 = w64b[kc * 4 + quad];
        const int rowb  = (kh + r) * 114;
        const int cioff = half * 32 + quad * 8;
        #pragma unroll
        for (int nt = 0; nt < 7; ++nt) {
            int col = nt * 16 + ln15 + kw;
            long bfrag = *(const long*)&xs[(rowb + col) * 72 + cioff];
            acc[0][nt] = __builtin_amdgcn_mfma_i32_16x16x32_i8(a0, bfrag, acc[0][nt], 0, 0, 0);
            acc[1][nt] = __builtin_amdgcn_mfma_i32_16x16x32_i8(a1, bfrag, acc[1][nt], 0, 0, 0);
        }
    }

    const float s = ascale[0] * wscale[0];
    const int h = h0 + r;
    #pragma unroll
    for (int mt = 0; mt < 2; ++mt) {
        #pragma unroll
        for (int reg = 0; reg < 4; ++reg) {
            int co = cobase + mt * 16 + quad * 4 + reg;
            float bv = bias[co];
            float* op = out + ((size_t)(b * COUT_ + co) * HH + h) * WW;
            #pragma unroll
            for (int nt = 0; nt < 7; ++nt) {
                int wp = nt * 16 + ln15;
                op[wp] = (float)acc[mt][nt][reg] * s + bv;
            }
        }
    }
}

extern "C" void kernel_launch(void* const* d_in, const int* in_sizes, int n_in,
                              void* d_out, int out_size, void* d_ws, size_t ws_size,
                              hipStream_t stream) {
    const int*    xq     = (const int*)d_in[0];
    const int*    wq     = (const int*)d_in[1];
    const float*  wscale = (const float*)d_in[2];
    const float*  ascale = (const float*)d_in[3];
    const float*  bias   = (const float*)d_in[4];
    int8_t* ws  = (int8_t*)d_ws;
    float*  out = (float*)d_out;

    if (ws_size >= (size_t)XT_NEED) {
        xtrans_kernel<<<6872, 256, 0, stream>>>(xq, wq, ws);
        conv2_kernel<<<BATCH * 56, 256, 0, stream>>>(ws, wscale, ascale, bias, out);
    } else {
        wtrans_kernel<<<144, 256, 0, stream>>>(wq, ws);
        conv_kernel<<<BATCH * 56, 256, 0, stream>>>(xq, ws, wscale, ascale, bias, out);
    }
}

// Round 4
// 205.011 us; speedup vs baseline: 1.0491x; 1.0491x over previous
//
#include <hip/hip_runtime.h>
#include <stdint.h>

#define BATCH 32
#define CIN   64
#define HH    112
#define WW    112
#define COUT_ 64

typedef int v4i __attribute__((ext_vector_type(4)));

// d_ws layout
#define WT_OFF   0                      // 36,864 B  weights [co][tap][ci]
#define ZP_OFF   36864                  // 7,296 B   zeroed pad row
#define XT_OFF   65536                  // 26,167,296 B  x int8 [b][h][114 cols][64 ci, swizzled]
#define XT_NEED  (65536 + 26167296)

#define XS_TILE  29184                  // 4 rows * 114 cols * 64 B

// Fallback-path weight transpose (also used standalone when ws is small).
__global__ void wtrans_kernel(const int* __restrict__ wq, int8_t* __restrict__ wt) {
    int idx = blockIdx.x * 256 + threadIdx.x;   // 0 .. 36863, exact
    int ci   = idx & 63;
    int khkw = (idx >> 6) % 9;
    int co   = idx / 576;
    wt[idx] = (int8_t)wq[co * 576 + ci * 9 + khkw];
}

// Fused pre-pass: x narrow+NCHW->NHWC transpose (W-pad baked in, ci-chunks
// XOR-swizzled by (col>>1)&3 for conflict-free conv ds_read_b128), pad-col
// zeroing, H-pad zero row, and the weight transpose — one launch.
__global__ void xtrans_kernel(const int* __restrict__ x, const int* __restrict__ wq,
                              int8_t* __restrict__ ws) {
    int8_t* __restrict__ xt = ws + XT_OFF;
    const int bid = blockIdx.x;
    const int tid = threadIdx.x;
    if (bid < 6272) {
        // 32 b x 112 h x 28 colgroups x 16 cigroups = 1,605,632 jobs, exact
        int idx  = bid * 256 + tid;
        int ci4  = idx & 15;            // dword index within the 64B pixel
        int rest = idx >> 4;
        int cg   = rest % 28;           // w = cg*4
        int bh   = rest / 28;           // b*112 + h
        int h    = bh % 112;
        int b    = bh / 112;
        const v4i* gp = (const v4i*)(x + ((b * CIN + ci4 * 4) * HH + h) * WW + cg * 4);
        v4i q0 = gp[0];
        v4i q1 = gp[3136];              // +1 ci plane (112*112/4 int4s)
        v4i q2 = gp[2 * 3136];
        v4i q3 = gp[3 * 3136];
        int8_t* rowp = xt + (size_t)bh * 114 * 64;
        #pragma unroll
        for (int j = 0; j < 4; ++j) {
            uint32_t lo01 = __builtin_amdgcn_perm((uint32_t)q1[j], (uint32_t)q0[j], 0x0C0C0400u);
            uint32_t lo23 = __builtin_amdgcn_perm((uint32_t)q3[j], (uint32_t)q2[j], 0x04000C0Cu);
            int col = cg * 4 + 1 + j;   // +1: W-pad shift
            // chunk (ci4>>2) -> slot (chunk ^ ((col>>1)&3)); dword-in-chunk keeps (ci4&3)
            int sd  = (((ci4 >> 2) ^ ((col >> 1) & 3)) << 2) | (ci4 & 3);
            *(uint32_t*)&rowp[col * 64 + sd * 4] = lo01 | lo23;
        }
    } else if (bid < 6720) {
        // zero pad columns 0 and 113: 32*112*2*16 dwords = 114,688 jobs, exact
        int idx  = (bid - 6272) * 256 + tid;
        int d    = idx & 15;
        int side = (idx >> 4) & 1;
        int bh   = idx >> 5;
        int col  = side ? 113 : 0;
        *(uint32_t*)&xt[((size_t)bh * 114 + col) * 64 + d * 4] = 0u;
    } else if (bid < 6728) {
        // zero the H-pad row (1,824 dwords)
        int idx = (bid - 6720) * 256 + tid;
        if (idx < 1824) *(uint32_t*)&ws[ZP_OFF + idx * 4] = 0u;
    } else {
        // weight transpose: [co][ci][kh][kw] -> [co][tap][ci], 36,864 jobs exact
        int idx  = (bid - 6728) * 256 + tid;
        int ci   = idx & 63;
        int khkw = (idx >> 6) % 9;
        int co   = idx / 576;
        ws[WT_OFF + idx] = (int8_t)wq[co * 576 + ci * 9 + khkw];
    }
}

// Main conv kernel v5: software-pipelined multi-tile blocks (T3 2-phase).
// Each block owns 4 consecutive (b, 2-row) tiles; LDS double-buffered.
// Iter t: issue DMA for tile t+1, MFMA tile t, vmcnt(0)+s_barrier (everything
// outstanding is a full phase old), THEN store tile t (overlaps next DMA).
__launch_bounds__(256, 2)
__global__ void conv3_kernel(const int8_t* __restrict__ ws,
                             const float*  __restrict__ wscale,
                             const float*  __restrict__ ascale,
                             const float*  __restrict__ bias,
                             float*        __restrict__ out) {
    __shared__ int8_t xs[2][XS_TILE];   // 58,368 B -> 2 blocks/CU

    const int tid = threadIdx.x;
    // XCD-chunked swizzle: 448 blocks = 8 XCDs x 56 contiguous tile-groups.
    // Per XCD: 4 batches' xt (3.27 MB) -> fits a 4 MB L2.
    const int bt     = ((blockIdx.x & 7) * 56) + (blockIdx.x >> 3);
    const int b      = bt / 14;
    const int h0base = (bt % 14) * 8;   // 4 tiles of 2 rows = 8 rows

    const int8_t* __restrict__ xt = ws + XT_OFF;
    const int8_t* __restrict__ zp = ws + ZP_OFF;
    const int8_t* __restrict__ wt = ws + WT_OFF;

    const int lane = tid & 63;
    const int wave = tid >> 6;            // co-tile 0..3
    const int ln15 = lane & 15;
    const int quad = lane >> 4;

    // preload A fragments: wt[co][tap*64 + quad*16 .. +15]
    const v4i* wrow = (const v4i*)(wt + (size_t)(wave * 16 + ln15) * 576);
    v4i a[9];
    #pragma unroll
    for (int t = 0; t < 9; ++t) a[t] = wrow[t * 4 + quad];

    // preload scale + bias (keeps the epilogue store-only: exact vmem counts)
    const float s = ascale[0] * wscale[0];
    float bv[4];
    #pragma unroll
    for (int reg = 0; reg < 4; ++reg) bv[reg] = bias[wave * 16 + quad * 4 + reg];

    // DMA one 4-row tile (1824 x 16B chunks) into xs[buf]
    auto stage = [&](int buf, int t) {
        const int h0 = h0base + 2 * t;
        #pragma unroll
        for (int i = 0; i < 8; ++i) {
            int idx = tid + i * 256;
            if (idx < 1824) {
                int row = idx / 456;          // 456 chunks per row
                int rem = idx - row * 456;
                int hh  = h0 - 1 + row;
                const int8_t* src = (hh >= 0 && hh < HH)
                    ? xt + ((size_t)(b * HH + hh) * 7296 + rem * 16)
                    : zp + rem * 16;
                __builtin_amdgcn_global_load_lds(
                    (const __attribute__((address_space(1))) int*)src,
                    (__attribute__((address_space(3))) int*)(&xs[buf][idx * 16]),
                    16, 0, 0);
            }
        }
    };

    // prologue: fill buffer 0
    stage(0, 0);
    asm volatile("s_waitcnt vmcnt(0)" ::: "memory");
    __builtin_amdgcn_s_barrier();
    __builtin_amdgcn_sched_barrier(0);

    int cur = 0;
    #pragma unroll 1
    for (int t = 0; t < 4; ++t) {
        if (t < 3) stage(cur ^ 1, t + 1);   // next-tile DMA in flight during MFMA

        v4i acc[2][7];
        #pragma unroll
        for (int r = 0; r < 2; ++r)
            #pragma unroll
            for (int nt = 0; nt < 7; ++nt)
                acc[r][nt] = (v4i){0, 0, 0, 0};

        const int8_t* xsb = &xs[cur][0];
        // each bfrag serves acc[0] (kh=rho) and acc[1] (kh=rho-1) at same kw:
        // 84 ds_read_b128 : 126 MFMA per wave per tile, conflict-free swizzle.
        #pragma unroll
        for (int rho = 0; rho < 4; ++rho) {
            #pragma unroll
            for (int kw = 0; kw < 3; ++kw) {
                const int m   = ln15 + kw;                     // col within 16-col tile
                const int swz = (quad ^ ((m >> 1) & 3)) << 4;  // (col>>1)&3, nt*16-invariant
                const int8_t* bp = &xsb[(rho * 114 + m) * 64 + swz];
                #pragma unroll
                for (int nt = 0; nt < 7; ++nt) {
                    v4i bfrag = *(const v4i*)(bp + nt * 1024);
                    if (rho <= 2)
                        acc[0][nt] = __builtin_amdgcn_mfma_i32_16x16x64_i8(
                            a[rho * 3 + kw], bfrag, acc[0][nt], 0, 0, 0);
                    if (rho >= 1)
                        acc[1][nt] = __builtin_amdgcn_mfma_i32_16x16x64_i8(
                            a[(rho - 1) * 3 + kw], bfrag, acc[1][nt], 0, 0, 0);
                }
            }
        }

        // fence: keep compute (incl. its lgkmcnt waits) before the barrier,
        // so all LDS reads of xs[cur] are complete when any wave passes it.
        __builtin_amdgcn_sched_barrier(0);
        if (t < 3) {
            // Outstanding here: loads(t+1) + stores(t-1), all >= one full
            // compute phase old -> near-free drain. No young stores counted.
            asm volatile("s_waitcnt vmcnt(0)" ::: "memory");
            __builtin_amdgcn_s_barrier();
            __builtin_amdgcn_sched_barrier(0);
        }

        // epilogue stores for tile t — overlap tile t+1's DMA + MFMA
        const int h0 = h0base + 2 * t;
        #pragma unroll
        for (int r = 0; r < 2; ++r) {
            const int h = h0 + r;
            #pragma unroll
            for (int reg = 0; reg < 4; ++reg) {
                int co = wave * 16 + quad * 4 + reg;
                float* op = out + ((size_t)(b * COUT_ + co) * HH + h) * WW;
                #pragma unroll
                for (int nt = 0; nt < 7; ++nt)
                    op[nt * 16 + ln15] = (float)acc[r][nt][reg] * s + bv[reg];
            }
        }
        cur ^= 1;
    }
}

// ---------------- fallback path (small workspace): previous proven kernel ----
__launch_bounds__(256, 2)
__global__ void conv_kernel(const int* __restrict__ x,
                            const int8_t* __restrict__ wt,
                            const float*  __restrict__ wscale,
                            const float*  __restrict__ ascale,
                            const float*  __restrict__ bias,
                            float*        __restrict__ out) {
    __shared__ int8_t xs[4 * 114 * 72];   // 32,832 B

    const int tid = threadIdx.x;
    const int bt  = blockIdx.x;
    const int b   = bt / 56;
    const int h0  = (bt % 56) * 2;

    #pragma unroll
    for (int it = 0; it < 7; ++it) {
        int job = tid + it * 256;
        int ci4 = job & 15;
        int cg  = (job >> 4) % 28;
        int row = job / 448;
        int hh  = h0 - 1 + row;
        v4i q0 = {0,0,0,0}, q1 = {0,0,0,0}, q2 = {0,0,0,0}, q3 = {0,0,0,0};
        if (hh >= 0 && hh < HH) {
            const v4i* gp = (const v4i*)
                (x + ((size_t)(b * CIN + ci4 * 4) * HH + hh) * WW + cg * 4);
            q0 = gp[0];
            q1 = gp[3136];
            q2 = gp[2 * 3136];
            q3 = gp[3 * 3136];
        }
        #pragma unroll
        for (int j = 0; j < 4; ++j) {
            uint32_t lo01 = __builtin_amdgcn_perm((uint32_t)q1[j], (uint32_t)q0[j], 0x0C0C0400u);
            uint32_t lo23 = __builtin_amdgcn_perm((uint32_t)q3[j], (uint32_t)q2[j], 0x04000C0Cu);
            int addr = (row * 114 + cg * 4 + 1 + j) * 72 + ci4 * 4;
            *(uint32_t*)&xs[addr] = lo01 | lo23;
        }
    }
    if (tid < 128) {
        int ci4 = tid & 15;
        int col = ((tid >> 4) & 1) ? 113 : 0;
        int row = tid >> 5;
        *(uint32_t*)&xs[(row * 114 + col) * 72 + ci4 * 4] = 0u;
    }
    __syncthreads();

    const int lane = tid & 63;
    const int wave = tid >> 6;
    const int ln15 = lane & 15;
    const int quad = lane >> 4;
    const int r    = wave >> 1;
    const int coh  = wave & 1;
    const int cobase = coh * 32;

    v4i acc[2][7];
    #pragma unroll
    for (int mt = 0; mt < 2; ++mt)
        #pragma unroll
        for (int nt = 0; nt < 7; ++nt)
            acc[mt][nt] = (v4i){0, 0, 0, 0};

    const long* w64a = (const long*)(wt + (size_t)(cobase + ln15) * 576);
    const long* w64b = (const long*)(wt + (size_t)(cobase + 16 + ln15) * 576);

    #pragma unroll
    for (int kc = 0; kc < 18; ++kc) {
        const int khkw = kc >> 1;
        const int kh   = khkw / 3;
        const int kw   = khkw % 3;
        const int half = kc & 1;
        long a0 = w64a[kc * 4 + quad];
        long a1 = w64b[kc * 4 + quad];
        const int rowb  = (kh + r) * 114;
        const int cioff = half * 32 + quad * 8;
        #pragma unroll
        for (int nt = 0; nt < 7; ++nt) {
            int col = nt * 16 + ln15 + kw;
            long bfrag = *(const long*)&xs[(rowb + col) * 72 + cioff];
            acc[0][nt] = __builtin_amdgcn_mfma_i32_16x16x32_i8(a0, bfrag, acc[0][nt], 0, 0, 0);
            acc[1][nt] = __builtin_amdgcn_mfma_i32_16x16x32_i8(a1, bfrag, acc[1][nt], 0, 0, 0);
        }
    }

    const float s = ascale[0] * wscale[0];
    const int h = h0 + r;
    #pragma unroll
    for (int mt = 0; mt < 2; ++mt) {
        #pragma unroll
        for (int reg = 0; reg < 4; ++reg) {
            int co = cobase + mt * 16 + quad * 4 + reg;
            float bv = bias[co];
            float* op = out + ((size_t)(b * COUT_ + co) * HH + h) * WW;
            #pragma unroll
            for (int nt = 0; nt < 7; ++nt) {
                int wp = nt * 16 + ln15;
                op[wp] = (float)acc[mt][nt][reg] * s + bv;
            }
        }
    }
}

extern "C" void kernel_launch(void* const* d_in, const int* in_sizes, int n_in,
                              void* d_out, int out_size, void* d_ws, size_t ws_size,
                              hipStream_t stream) {
    const int*    xq     = (const int*)d_in[0];
    const int*    wq     = (const int*)d_in[1];
    const float*  wscale = (const float*)d_in[2];
    const float*  ascale = (const float*)d_in[3];
    const float*  bias   = (const float*)d_in[4];
    int8_t* ws  = (int8_t*)d_ws;
    float*  out = (float*)d_out;

    if (ws_size >= (size_t)XT_NEED) {
        xtrans_kernel<<<6872, 256, 0, stream>>>(xq, wq, ws);
        conv3_kernel<<<448, 256, 0, stream>>>(ws, wscale, ascale, bias, out);
    } else {
        wtrans_kernel<<<144, 256, 0, stream>>>(wq, ws);
        conv_kernel<<<BATCH * 56, 256, 0, stream>>>(xq, ws, wscale, ascale, bias, out);
    }
}

// Round 5
// 200.342 us; speedup vs baseline: 1.0736x; 1.0233x over previous
//
#include <hip/hip_runtime.h>
#include <stdint.h>

#define BATCH 32
#define CIN   64
#define HH    112
#define WW    112
#define COUT_ 64

typedef int v4i __attribute__((ext_vector_type(4)));

// d_ws: only the transposed weights now. 36,864 B.
#define WT_OFF   0

// Weight transpose: [co][ci][kh][kw] -> [co][tap][ci] so A-fragments
// (16 consecutive k = contiguous ci at a fixed tap) are direct loads.
__global__ void wtrans_kernel(const int* __restrict__ wq, int8_t* __restrict__ wt) {
    int idx = blockIdx.x * 256 + threadIdx.x;   // 0 .. 36863, exact
    int ci   = idx & 63;
    int khkw = (idx >> 6) % 9;
    int co   = idx / 576;
    wt[idx] = (int8_t)wq[co * 576 + ci * 9 + khkw];
}

// Fused conv kernel v6: single pass, no intermediate tensor.
// 256 blocks = 32 batches x 8 h-groups (1 block/CU, exact balance).
// Each block: 7 tiles of 2 output rows. LDS = 8-row int8 ring buffer;
// per tile only the 2 NEW input rows are staged (int32 -> int8 narrowing
// in registers via v_perm, T14 split: loads issued before MFMA, narrow+
// ds_write after). Ring row phys(hh) = (hh - (hb-1)) & 7:
//   tile t reads phys {2t..2t+3}&7, stages phys {2t+4,2t+5}&7 — disjoint,
//   and the staged rows were last read by tile t-2 (two barriers ago).
__launch_bounds__(256, 2)
__global__ void conv4_kernel(const int* __restrict__ x,
                             const int8_t* __restrict__ wt,
                             const float*  __restrict__ wscale,
                             const float*  __restrict__ ascale,
                             const float*  __restrict__ bias,
                             float*        __restrict__ out) {
    __shared__ int8_t xs[8 * 114 * 64];   // 58,368 B ring: 8 rows x 114 cols x 64 ci

    const int tid = threadIdx.x;
    const int b   = blockIdx.x >> 3;
    const int hb  = (blockIdx.x & 7) * 14;    // this block's 14 output rows

    const int lane = tid & 63;
    const int wave = tid >> 6;            // co-tile 0..3
    const int ln15 = lane & 15;
    const int quad = lane >> 4;

    // one-time: zero the W-pad columns 0 and 113 of all 8 ring rows
    // (8 rows x 2 cols x 16 dwords = 256 jobs, exact; staging never touches them)
    {
        int pr   = tid >> 5;
        int side = (tid >> 4) & 1;
        int d    = tid & 15;
        *(uint32_t*)&xs[pr * 7296 + (side ? 113 : 0) * 64 + d * 4] = 0u;
    }

    // preload A fragments: wt[co][tap*64 + quad*16 .. +15]
    const v4i* wrow = (const v4i*)(wt + (size_t)(wave * 16 + ln15) * 576);
    v4i a[9];
    #pragma unroll
    for (int t = 0; t < 9; ++t) a[t] = wrow[t * 4 + quad];

    const float s = ascale[0] * wscale[0];
    float bv[4];
    #pragma unroll
    for (int reg = 0; reg < 4; ++reg) bv[reg] = bias[wave * 16 + quad * 4 + reg];

    // ---- 2-row staging, split into load (to regs) and write (narrow->LDS) ----
    // 896 jobs = 2 rows x 28 colgroups x 16 ci4; job: 4 int4 loads (4 ci-planes
    // x 4 pixels). Within a wave, lanes {i,i+16,i+32,i+48} cover one full 64B
    // line per (ci4,p) -> coalesced. OOB rows stay zero (H padding).
    v4i q[16];
    auto stage_load = [&](int hstart) {
        #pragma unroll
        for (int it = 0; it < 4; ++it) {
            #pragma unroll
            for (int p = 0; p < 4; ++p) q[it * 4 + p] = (v4i){0, 0, 0, 0};
            int job = tid + it * 256;
            if (job < 896) {
                int ci4  = job & 15;
                int cg   = (job >> 4) % 28;
                int row2 = job / 448;
                int hh   = hstart + row2;
                if (hh >= 0 && hh < HH) {
                    const v4i* gp = (const v4i*)
                        (x + ((size_t)(b * CIN + ci4 * 4) * HH + hh) * WW + cg * 4);
                    q[it * 4 + 0] = gp[0];
                    q[it * 4 + 1] = gp[3136];      // +1 ci plane (112*112/4 int4s)
                    q[it * 4 + 2] = gp[2 * 3136];
                    q[it * 4 + 3] = gp[3 * 3136];
                }
            }
        }
    };
    // narrow + swizzled LDS write. Per-instr bank pattern: 16 lanes = 16
    // distinct dwords of one 64B pixel (bijective sd) -> conflict-free.
    auto stage_write = [&](int pb) {
        #pragma unroll
        for (int it = 0; it < 4; ++it) {
            int job = tid + it * 256;
            if (job < 896) {
                int ci4  = job & 15;
                int cg   = (job >> 4) % 28;
                int row2 = job / 448;
                int pr   = (pb + row2) & 7;
                int8_t* rowp = &xs[pr * 7296];
                #pragma unroll
                for (int j = 0; j < 4; ++j) {
                    uint32_t lo01 = __builtin_amdgcn_perm(
                        (uint32_t)q[it * 4 + 1][j], (uint32_t)q[it * 4 + 0][j], 0x0C0C0400u);
                    uint32_t lo23 = __builtin_amdgcn_perm(
                        (uint32_t)q[it * 4 + 3][j], (uint32_t)q[it * 4 + 2][j], 0x04000C0Cu);
                    int col = cg * 4 + 1 + j;   // +1: W-pad shift
                    int sd  = (((ci4 >> 2) ^ ((col >> 1) & 3)) << 2) | (ci4 & 3);
                    *(uint32_t*)&rowp[col * 64 + sd * 4] = lo01 | lo23;
                }
            }
        }
    };

    // ---- prologue: stage the first 4 rows (phys 0..3 = hh hb-1..hb+2) ----
    stage_load(hb - 1);
    asm volatile("s_waitcnt vmcnt(0)" ::: "memory");
    stage_write(0);
    stage_load(hb + 1);
    asm volatile("s_waitcnt vmcnt(0)" ::: "memory");
    stage_write(2);
    asm volatile("s_waitcnt lgkmcnt(0)" ::: "memory");
    __builtin_amdgcn_s_barrier();
    __builtin_amdgcn_sched_barrier(0);

    #pragma unroll 1
    for (int t = 0; t < 7; ++t) {
        // issue next tile's row loads; MFMA below hides their latency
        if (t < 6) {
            stage_load(hb + 2 * t + 3);
            __builtin_amdgcn_sched_barrier(0);
        }

        v4i acc[2][7];
        #pragma unroll
        for (int r = 0; r < 2; ++r)
            #pragma unroll
            for (int nt = 0; nt < 7; ++nt)
                acc[r][nt] = (v4i){0, 0, 0, 0};

        // each bfrag serves acc[0] (kh=rho) and acc[1] (kh=rho-1) at same kw:
        // 84 ds_read_b128 : 126 MFMA per wave per tile, conflict-free swizzle.
        #pragma unroll
        for (int rho = 0; rho < 4; ++rho) {
            const int pr = (2 * t + rho) & 7;
            #pragma unroll
            for (int kw = 0; kw < 3; ++kw) {
                const int m   = ln15 + kw;                     // col within 16-col tile
                const int swz = (quad ^ ((m >> 1) & 3)) << 4;  // (col>>1)&3, nt*16-invariant
                const int8_t* bp = &xs[pr * 7296 + m * 64 + swz];
                #pragma unroll
                for (int nt = 0; nt < 7; ++nt) {
                    v4i bfrag = *(const v4i*)(bp + nt * 1024);
                    if (rho <= 2)
                        acc[0][nt] = __builtin_amdgcn_mfma_i32_16x16x64_i8(
                            a[rho * 3 + kw], bfrag, acc[0][nt], 0, 0, 0);
                    if (rho >= 1)
                        acc[1][nt] = __builtin_amdgcn_mfma_i32_16x16x64_i8(
                            a[(rho - 1) * 3 + kw], bfrag, acc[1][nt], 0, 0, 0);
                }
            }
        }

        __builtin_amdgcn_sched_barrier(0);
        if (t < 6) {
            // loads of t+1 are the youngest vmem; everything else outstanding
            // (stores of t-1) is a full MFMA phase old -> near-free drain.
            asm volatile("s_waitcnt vmcnt(0)" ::: "memory");
            stage_write((2 * t + 4) & 7);   // disjoint from this tile's read rows
            asm volatile("s_waitcnt lgkmcnt(0)" ::: "memory");
            __builtin_amdgcn_s_barrier();
            __builtin_amdgcn_sched_barrier(0);
        }

        // ---- stores for tile t — overlap next tile's loads + MFMA ----
        const int h0 = hb + 2 * t;
        #pragma unroll
        for (int r = 0; r < 2; ++r) {
            const int h = h0 + r;
            #pragma unroll
            for (int reg = 0; reg < 4; ++reg) {
                int co = wave * 16 + quad * 4 + reg;
                float* op = out + ((size_t)(b * COUT_ + co) * HH + h) * WW;
                #pragma unroll
                for (int nt = 0; nt < 7; ++nt)
                    op[nt * 16 + ln15] = (float)acc[r][nt][reg] * s + bv[reg];
            }
        }
    }
}

extern "C" void kernel_launch(void* const* d_in, const int* in_sizes, int n_in,
                              void* d_out, int out_size, void* d_ws, size_t ws_size,
                              hipStream_t stream) {
    const int*    xq     = (const int*)d_in[0];
    const int*    wq     = (const int*)d_in[1];
    const float*  wscale = (const float*)d_in[2];
    const float*  ascale = (const float*)d_in[3];
    const float*  bias   = (const float*)d_in[4];
    int8_t* wt  = (int8_t*)d_ws;          // 36,864 B scratch
    float*  out = (float*)d_out;

    wtrans_kernel<<<144, 256, 0, stream>>>(wq, wt);
    conv4_kernel<<<256, 256, 0, stream>>>(xq, wt, wscale, ascale, bias, out);
}